// Round 1
// baseline (1082.228 us; speedup 1.0000x reference)
//
#include <hip/hip_runtime.h>
#include <hip/hip_fp16.h>

#define BB 256
#define SS 512
#define EE_N 20000
typedef _Float16 f16;

__device__ __forceinline__ float sigm(float x) { return 1.0f / (1.0f + __expf(-x)); }

// ---------------- K0: small folds ----------------
// blocks 0..499: Se rows; 500..501: Re; 502: Te+cbias; 503..630: Wcat top (copies);
// 631..758: Wcat bottom (W_b2 folds); 759..886: M_lnb; 887: bias consts.
__global__ __launch_bounds__(128) void k0_folds(
    const float* skill_emb, const float* response_emb,
    const float* W_time, const float* b_time,
    const float* W_int, const float* b_int,
    const float* W_b2, const float* b_b2,
    const float* W_learn, const float* b_learn,
    const float* W_forget, const float* b_forget,
    float* Se, float* Re, float* Te, float* cbias,
    float* c_lg, float* c_fg, float* fix_l,
    float* Wcat, float* M_lnb) {
  int blk = blockIdx.x, j = threadIdx.x;
  if (blk < 500) {
    float a = 0.f;
    for (int k = 0; k < 128; k++) a += skill_emb[blk * 128 + k] * W_int[(128 + k) * 128 + j];
    Se[blk * 128 + j] = a;
  } else if (blk < 502) {
    int i = blk - 500; float a = 0.f;
    for (int k = 0; k < 128; k++) a += response_emb[i * 128 + k] * W_int[(384 + k) * 128 + j];
    Re[i * 128 + j] = a;
  } else if (blk == 502) {
    float a = 0.f, c = 0.f;
    for (int k = 0; k < 128; k++) {
      float w = W_int[(256 + k) * 128 + j];
      a += W_time[k] * w; c += b_time[k] * w;
    }
    Te[j] = a; cbias[j] = b_int[j] + c;
  } else if (blk < 503 + 128) {
    int k = blk - 503;
    Wcat[k * 256 + j]       = W_learn[(128 + k) * 128 + j];
    Wcat[k * 256 + 128 + j] = W_forget[(128 + k) * 128 + j];
  } else if (blk < 631 + 128) {
    int k = blk - 631; float a = 0.f, c = 0.f;
    for (int m = 0; m < 128; m++) {
      float w = W_b2[k * 128 + m];
      a += w * (W_learn[(257 + m) * 128 + j] + W_learn[(385 + m) * 128 + j]);
      c += w * W_forget[(384 + m) * 128 + j];
    }
    Wcat[(128 + k) * 256 + j] = a;
    Wcat[(128 + k) * 256 + 128 + j] = c;
  } else if (blk < 759 + 128) {
    int k = blk - 759; float a = 0.f;
    for (int m = 0; m < 128; m++) a += W_b2[k * 128 + m] * W_learn[(385 + m) * 128 + j];
    M_lnb[k * 128 + j] = a;
  } else {
    float a = 0.f, c = 0.f, f = 0.f;
    for (int m = 0; m < 128; m++) {
      float w = b_b2[m];
      a += w * (W_learn[(257 + m) * 128 + j] + W_learn[(385 + m) * 128 + j]);
      c += w * W_forget[(384 + m) * 128 + j];
      f += w * W_learn[(385 + m) * 128 + j];
    }
    c_lg[j] = b_learn[j] + a;
    c_fg[j] = b_forget[j] + c;
    fix_l[j] = f;
  }
}

// ---------------- K1: Ee = exercise_emb @ W_int[0:128,:] ----------------
__global__ __launch_bounds__(256) void k1_Ee(const float* ex_emb, const float* W_int, float* Ee) {
  __shared__ float es[8 * 128];
  int tid = threadIdx.x, blk = blockIdx.x;
  *(float4*)&es[tid * 4] = *(const float4*)&ex_emb[blk * 1024 + tid * 4];
  __syncthreads();
  int d = tid & 127, rg = tid >> 7;
  float a0 = 0, a1 = 0, a2 = 0, a3 = 0;
  for (int k = 0; k < 128; k++) {
    float w = W_int[k * 128 + d];
    a0 += es[(rg * 4 + 0) * 128 + k] * w;
    a1 += es[(rg * 4 + 1) * 128 + k] * w;
    a2 += es[(rg * 4 + 2) * 128 + k] * w;
    a3 += es[(rg * 4 + 3) * 128 + k] * w;
  }
  Ee[(blk * 8 + rg * 4 + 0) * 128 + d] = a0;
  Ee[(blk * 8 + rg * 4 + 1) * 128 + d] = a1;
  Ee[(blk * 8 + rg * 4 + 2) * 128 + d] = a2;
  Ee[(blk * 8 + rg * 4 + 3) * 128 + d] = a3;
}

// ---------------- K3: fused pre-activation GEMM ----------------
// X[row] = [ci(128) | rb(128)] computed on the fly; PRE[row] = X @ Wcat + extras.
__global__ __launch_bounds__(256) void k3_gemm(
    const int* ex_seq, const int* sk_seq, const int* re_seq,
    const float* time_seq, const float* interval_seq,
    const float* att_seq, const float* hint_seq,
    const float* W_b1, const float* b_b1,
    const float* W_learn,
    const float* Ee, const float* Se, const float* Re,
    const float* Te, const float* cbias,
    const float* c_lg, const float* c_fg,
    const float* Wcat, f16* PRE) {
  __shared__ float As[32][257];
  __shared__ float Bs[32][256];
  int tid = threadIdx.x;
  int rowbase = blockIdx.x * 32;
  {
    int r = tid & 31, kseg = tid >> 5;
    int row = rowbase + r;
    if (kseg < 4) {
      int ex = ex_seq[row], sk = sk_seq[row], rp = re_seq[row];
      float tm = time_seq[row];
      const float* ee = Ee + ex * 128;
      const float* se = Se + sk * 128;
      const float* re = Re + rp * 128;
      for (int i = 0; i < 32; i++) {
        int k = kseg * 32 + i;
        float v = ee[k] + se[k] + tm * Te[k] + re[k] + cbias[k];
        As[r][k] = fmaxf(v, 0.f);
      }
    } else {
      float at = att_seq[row], hi = hint_seq[row];
      for (int i = 0; i < 32; i++) {
        int k2 = (kseg - 4) * 32 + i;
        float v = at * W_b1[k2] + hi * W_b1[128 + k2] + b_b1[k2];
        As[r][128 + k2] = fmaxf(v, 0.f);
      }
    }
  }
  float acc[8][4] = {};
  int colbase = (tid & 63) * 4;
  int rowsel = (tid >> 6) * 8;
  for (int kt = 0; kt < 8; kt++) {
    __syncthreads();
    for (int it = 0; it < 32; it++) Bs[it][tid] = Wcat[(kt * 32 + it) * 256 + tid];
    __syncthreads();
    int kb = kt * 32;
    for (int k = 0; k < 32; k++) {
      float4 bv = *(float4*)&Bs[k][colbase];
      #pragma unroll
      for (int r = 0; r < 8; r++) {
        float a = As[rowsel + r][kb + k];
        acc[r][0] += a * bv.x; acc[r][1] += a * bv.y;
        acc[r][2] += a * bv.z; acc[r][3] += a * bv.w;
      }
    }
  }
  for (int r = 0; r < 8; r++) {
    int row = rowbase + rowsel + r;
    float iv = interval_seq[row];
    #pragma unroll
    for (int c = 0; c < 4; c++) {
      int jj = colbase + c;
      float add = (jj < 128) ? (iv * W_learn[256 * 128 + jj] + c_lg[jj]) : c_fg[jj - 128];
      PRE[row * 256 + jj] = (f16)(acc[r][c] + add);
    }
  }
}

// ---------------- K4: last-step nb fixup ----------------
__global__ __launch_bounds__(128) void k4_fix(
    const float* att_seq, const float* hint_seq,
    const float* W_b1, const float* b_b1,
    const float* M_lnb, const float* fix_l, f16* PRE) {
  int b = blockIdx.x, j = threadIdx.x;
  int row = b * SS + (SS - 1);
  __shared__ float rb_s[128];
  float v = att_seq[row] * W_b1[j] + hint_seq[row] * W_b1[128 + j] + b_b1[j];
  rb_s[j] = fmaxf(v, 0.f);
  __syncthreads();
  float a = fix_l[j];
  for (int m = 0; m < 128; m++) a += rb_s[m] * M_lnb[m * 128 + j];
  PRE[row * 256 + j] = (f16)((float)PRE[row * 256 + j] - a);
}

// ---------------- K5: sequential scan (one block per batch row) ----------------
__global__ __launch_bounds__(512) void k5_scan(
    const f16* PRE, const float* W_learn, const float* W_forget, f16* h_hist) {
  int b = blockIdx.x;
  int j = threadIdx.x & 127, kk = threadIdx.x >> 7;
  float wl[32], wfh[32], wfl[32];
  #pragma unroll
  for (int i = 0; i < 32; i++) {
    int k = kk * 32 + i;
    wl[i]  = W_learn[k * 128 + j];
    wfh[i] = W_forget[k * 128 + j];
    wfl[i] = W_forget[(256 + k) * 128 + j];
  }
  __shared__ float h_s[128], lg_s[128], pf_s[128], part[3][128];
  if (kk == 0) h_s[j] = 0.f;
  __syncthreads();
  const f16* pre_b = PRE + (size_t)b * SS * 256;
  f16* hh = h_hist + (size_t)b * SS * 128;
  for (int t = 0; t < SS; t++) {
    float pl = 0.f, pf = 0.f;
    if (kk == 0) pl = (float)pre_b[t * 256 + j];
    if (kk == 1) pf = (float)pre_b[t * 256 + 128 + j];
    float a0 = 0.f, a1 = 0.f;
    #pragma unroll
    for (int i = 0; i < 32; i += 2) {
      a0 += h_s[kk * 32 + i] * wl[i];
      a1 += h_s[kk * 32 + i + 1] * wl[i + 1];
    }
    float a = a0 + a1;
    if (kk) part[kk - 1][j] = a;
    if (kk == 1) pf_s[j] = pf;
    __syncthreads();
    if (kk == 0) {
      float x = a + part[0][j] + part[1][j] + part[2][j] + pl;
      lg_s[j] = sigm(x);
    }
    __syncthreads();
    float c0 = 0.f, c1 = 0.f;
    #pragma unroll
    for (int i = 0; i < 32; i++) {
      int k = kk * 32 + i;
      c0 += h_s[k] * wfh[i];
      c1 += lg_s[k] * wfl[i];
    }
    float c = c0 + c1;
    if (kk) part[kk - 1][j] = c;
    __syncthreads();
    if (kk == 0) {
      float y = c + part[0][j] + part[1][j] + part[2][j] + pf_s[j];
      float fg = sigm(y);
      float hn = lg_s[j] + fg * h_s[j];
      hh[t * 128 + j] = (f16)hn;
      h_s[j] = hn;
    }
    __syncthreads();
  }
}

// ---------------- K6: prediction dot-products ----------------
__global__ __launch_bounds__(256) void k6_pred(
    const f16* h_hist, const int* ex_seq, const float* ex_emb,
    const float* W_pred, const float* b_pred, float* out) {
  int tid = threadIdx.x;
  int w = tid >> 6, lane = tid & 63, sub = lane >> 5, li = lane & 31;
  int row = blockIdx.x * 8 + w * 2 + sub;
  int ex = ex_seq[row];
  const f16* hp = h_hist + (size_t)row * 128 + li * 4;
  const float* ep = ex_emb + (size_t)ex * 128 + li * 4;
  float s = 0.f;
  #pragma unroll
  for (int q = 0; q < 4; q++) {
    int d = li * 4 + q;
    s += (float)hp[q] * W_pred[d];
    s += ep[q] * W_pred[128 + d];
  }
  #pragma unroll
  for (int m = 1; m < 32; m <<= 1) s += __shfl_xor(s, m, 64);
  if (li == 0) out[row] = sigm(s + b_pred[0]);
}

extern "C" void kernel_launch(void* const* d_in, const int* in_sizes, int n_in,
                              void* d_out, int out_size, void* d_ws, size_t ws_size,
                              hipStream_t stream) {
  const int*   ex_seq   = (const int*)d_in[0];
  const int*   sk_seq   = (const int*)d_in[1];
  const int*   re_seq   = (const int*)d_in[2];
  const float* time_seq = (const float*)d_in[3];
  const float* interval_seq = (const float*)d_in[4];
  const float* att_seq  = (const float*)d_in[5];
  const float* hint_seq = (const float*)d_in[6];
  // d_in[7] q_matrix: unused by the reference forward
  const float* ex_emb   = (const float*)d_in[8];
  const float* sk_emb   = (const float*)d_in[9];
  const float* re_emb   = (const float*)d_in[10];
  const float* W_time   = (const float*)d_in[11];
  const float* b_time   = (const float*)d_in[12];
  const float* W_int    = (const float*)d_in[13];
  const float* b_int    = (const float*)d_in[14];
  const float* W_b1     = (const float*)d_in[15];
  const float* b_b1     = (const float*)d_in[16];
  const float* W_b2     = (const float*)d_in[17];
  const float* b_b2     = (const float*)d_in[18];
  const float* W_learn  = (const float*)d_in[19];
  const float* b_learn  = (const float*)d_in[20];
  const float* W_forget = (const float*)d_in[21];
  const float* b_forget = (const float*)d_in[22];
  const float* W_pred   = (const float*)d_in[23];
  const float* b_pred   = (const float*)d_in[24];

  char* ws = (char*)d_ws;
  float* Ee    = (float*)(ws);              // 20000*128 f32 = 10,240,000
  float* Se    = (float*)(ws + 10240000);   // 500*128 f32   =    256,000
  float* Re    = (float*)(ws + 10496000);   // 2*128 f32     =      1,024
  float* Te    = (float*)(ws + 10497024);   // 128 f32
  float* cbias = (float*)(ws + 10497536);
  float* c_lg  = (float*)(ws + 10498048);
  float* c_fg  = (float*)(ws + 10498560);
  float* fix_l = (float*)(ws + 10499072);
  float* Wcat  = (float*)(ws + 10499584);   // 256*256 f32 = 262,144
  float* M_lnb = (float*)(ws + 10761728);   // 128*128 f32 =  65,536
  f16*   PRE   = (f16*)  (ws + 10827264);   // 131072*256 f16 = 67,108,864
  f16*   h_hist= (f16*)  (ws + 77936128);   // 131072*128 f16 = 33,554,432
  // total = 111,490,560 bytes

  k0_folds<<<dim3(888), dim3(128), 0, stream>>>(
      sk_emb, re_emb, W_time, b_time, W_int, b_int, W_b2, b_b2,
      W_learn, b_learn, W_forget, b_forget,
      Se, Re, Te, cbias, c_lg, c_fg, fix_l, Wcat, M_lnb);
  k1_Ee<<<dim3(2500), dim3(256), 0, stream>>>(ex_emb, W_int, Ee);
  k3_gemm<<<dim3(4096), dim3(256), 0, stream>>>(
      ex_seq, sk_seq, re_seq, time_seq, interval_seq, att_seq, hint_seq,
      W_b1, b_b1, W_learn, Ee, Se, Re, Te, cbias, c_lg, c_fg, Wcat, PRE);
  k4_fix<<<dim3(256), dim3(128), 0, stream>>>(
      att_seq, hint_seq, W_b1, b_b1, M_lnb, fix_l, PRE);
  k5_scan<<<dim3(256), dim3(512), 0, stream>>>(PRE, W_learn, W_forget, h_hist);
  k6_pred<<<dim3(16384), dim3(256), 0, stream>>>(
      h_hist, ex_seq, ex_emb, W_pred, b_pred, (float*)d_out);
}

// Round 2
// 1047.800 us; speedup vs baseline: 1.0329x; 1.0329x over previous
//
#include <hip/hip_runtime.h>
#include <hip/hip_fp16.h>

#define BB 256
#define SS 512
#define EE_N 20000
typedef _Float16 f16;
typedef __attribute__((ext_vector_type(8))) _Float16 half8;
typedef __attribute__((ext_vector_type(4))) float f32x4;

__device__ __forceinline__ float sigm(float x) { return 1.0f / (1.0f + __expf(-x)); }

// ---------------- K0: small folds ----------------
__global__ __launch_bounds__(128) void k0_folds(
    const float* skill_emb, const float* response_emb,
    const float* W_time, const float* b_time,
    const float* W_int, const float* b_int,
    const float* W_b2, const float* b_b2,
    const float* W_learn, const float* b_learn,
    const float* W_forget, const float* b_forget,
    float* Se, float* Re, float* Te, float* cbias,
    float* c_lg, float* c_fg, float* fix_l,
    float* Wcat, float* M_lnb) {
  int blk = blockIdx.x, j = threadIdx.x;
  if (blk < 500) {
    float a = 0.f;
    for (int k = 0; k < 128; k++) a += skill_emb[blk * 128 + k] * W_int[(128 + k) * 128 + j];
    Se[blk * 128 + j] = a;
  } else if (blk < 502) {
    int i = blk - 500; float a = 0.f;
    for (int k = 0; k < 128; k++) a += response_emb[i * 128 + k] * W_int[(384 + k) * 128 + j];
    Re[i * 128 + j] = a;
  } else if (blk == 502) {
    float a = 0.f, c = 0.f;
    for (int k = 0; k < 128; k++) {
      float w = W_int[(256 + k) * 128 + j];
      a += W_time[k] * w; c += b_time[k] * w;
    }
    Te[j] = a; cbias[j] = b_int[j] + c;
  } else if (blk < 503 + 128) {
    int k = blk - 503;
    Wcat[k * 256 + j]       = W_learn[(128 + k) * 128 + j];
    Wcat[k * 256 + 128 + j] = W_forget[(128 + k) * 128 + j];
  } else if (blk < 631 + 128) {
    int k = blk - 631; float a = 0.f, c = 0.f;
    for (int m = 0; m < 128; m++) {
      float w = W_b2[k * 128 + m];
      a += w * (W_learn[(257 + m) * 128 + j] + W_learn[(385 + m) * 128 + j]);
      c += w * W_forget[(384 + m) * 128 + j];
    }
    Wcat[(128 + k) * 256 + j] = a;
    Wcat[(128 + k) * 256 + 128 + j] = c;
  } else if (blk < 759 + 128) {
    int k = blk - 759; float a = 0.f;
    for (int m = 0; m < 128; m++) a += W_b2[k * 128 + m] * W_learn[(385 + m) * 128 + j];
    M_lnb[k * 128 + j] = a;
  } else {
    float a = 0.f, c = 0.f, f = 0.f;
    for (int m = 0; m < 128; m++) {
      float w = b_b2[m];
      a += w * (W_learn[(257 + m) * 128 + j] + W_learn[(385 + m) * 128 + j]);
      c += w * W_forget[(384 + m) * 128 + j];
      f += w * W_learn[(385 + m) * 128 + j];
    }
    c_lg[j] = b_learn[j] + a;
    c_fg[j] = b_forget[j] + c;
    fix_l[j] = f;
  }
}

// ---------------- K1: Ee = exercise_emb @ W_int[0:128,:] ----------------
__global__ __launch_bounds__(256) void k1_Ee(const float* ex_emb, const float* W_int, float* Ee) {
  __shared__ float es[8 * 128];
  int tid = threadIdx.x, blk = blockIdx.x;
  *(float4*)&es[tid * 4] = *(const float4*)&ex_emb[blk * 1024 + tid * 4];
  __syncthreads();
  int d = tid & 127, rg = tid >> 7;
  float a0 = 0, a1 = 0, a2 = 0, a3 = 0;
  for (int k = 0; k < 128; k++) {
    float w = W_int[k * 128 + d];
    a0 += es[(rg * 4 + 0) * 128 + k] * w;
    a1 += es[(rg * 4 + 1) * 128 + k] * w;
    a2 += es[(rg * 4 + 2) * 128 + k] * w;
    a3 += es[(rg * 4 + 3) * 128 + k] * w;
  }
  Ee[(blk * 8 + rg * 4 + 0) * 128 + d] = a0;
  Ee[(blk * 8 + rg * 4 + 1) * 128 + d] = a1;
  Ee[(blk * 8 + rg * 4 + 2) * 128 + d] = a2;
  Ee[(blk * 8 + rg * 4 + 3) * 128 + d] = a3;
}

// ---------------- K2: weight -> MFMA B-fragment layout (f16) ----------------
// Wfrag[((mat*8 + w)*4 + t4)*64 + lane][e] = W_mat[t4*32 + (lane>>4)*8 + e][16w + (lane&15)]
// mat 0 = W_learn[0:128] (h->lg), 1 = W_forget[0:128] (h->fg), 2 = W_forget[256:384] (lg->fg)
__global__ __launch_bounds__(64) void k2_wprep(const float* W_learn, const float* W_forget, f16* Wfrag) {
  int blk = blockIdx.x;               // 0..95 = (mat*8 + w)*4 + t4
  int mat = blk >> 5, rem = blk & 31, w = rem >> 2, t4 = rem & 3;
  int lane = threadIdx.x;
  int cc = lane & 15, gg = lane >> 4;
  const float* src = (mat == 0) ? W_learn : (mat == 1 ? W_forget : W_forget + 256 * 128);
  f16* dst = Wfrag + ((size_t)blk * 64 + lane) * 8;
  #pragma unroll
  for (int e = 0; e < 8; e++) {
    int k = t4 * 32 + gg * 8 + e;
    int j = 16 * w + cc;
    dst[e] = (f16)src[k * 128 + j];
  }
}

// ---------------- K3: fused pre-activation GEMM ----------------
__global__ __launch_bounds__(256) void k3_gemm(
    const int* ex_seq, const int* sk_seq, const int* re_seq,
    const float* time_seq, const float* interval_seq,
    const float* att_seq, const float* hint_seq,
    const float* W_b1, const float* b_b1,
    const float* W_learn,
    const float* Ee, const float* Se, const float* Re,
    const float* Te, const float* cbias,
    const float* c_lg, const float* c_fg,
    const float* Wcat, f16* PRE) {
  __shared__ float As[32][257];
  __shared__ float Bs[32][256];
  int tid = threadIdx.x;
  int rowbase = blockIdx.x * 32;
  {
    int r = tid & 31, kseg = tid >> 5;
    int row = rowbase + r;
    if (kseg < 4) {
      int ex = ex_seq[row], sk = sk_seq[row], rp = re_seq[row];
      float tm = time_seq[row];
      const float* ee = Ee + ex * 128;
      const float* se = Se + sk * 128;
      const float* re = Re + rp * 128;
      for (int i = 0; i < 32; i++) {
        int k = kseg * 32 + i;
        float v = ee[k] + se[k] + tm * Te[k] + re[k] + cbias[k];
        As[r][k] = fmaxf(v, 0.f);
      }
    } else {
      float at = att_seq[row], hi = hint_seq[row];
      for (int i = 0; i < 32; i++) {
        int k2 = (kseg - 4) * 32 + i;
        float v = at * W_b1[k2] + hi * W_b1[128 + k2] + b_b1[k2];
        As[r][128 + k2] = fmaxf(v, 0.f);
      }
    }
  }
  float acc[8][4] = {};
  int colbase = (tid & 63) * 4;
  int rowsel = (tid >> 6) * 8;
  for (int kt = 0; kt < 8; kt++) {
    __syncthreads();
    for (int it = 0; it < 32; it++) Bs[it][tid] = Wcat[(kt * 32 + it) * 256 + tid];
    __syncthreads();
    int kb = kt * 32;
    for (int k = 0; k < 32; k++) {
      float4 bv = *(float4*)&Bs[k][colbase];
      #pragma unroll
      for (int r = 0; r < 8; r++) {
        float a = As[rowsel + r][kb + k];
        acc[r][0] += a * bv.x; acc[r][1] += a * bv.y;
        acc[r][2] += a * bv.z; acc[r][3] += a * bv.w;
      }
    }
  }
  for (int r = 0; r < 8; r++) {
    int row = rowbase + rowsel + r;
    float iv = interval_seq[row];
    #pragma unroll
    for (int c = 0; c < 4; c++) {
      int jj = colbase + c;
      float add = (jj < 128) ? (iv * W_learn[256 * 128 + jj] + c_lg[jj]) : c_fg[jj - 128];
      PRE[row * 256 + jj] = (f16)(acc[r][c] + add);
    }
  }
}

// ---------------- K4: last-step nb fixup ----------------
__global__ __launch_bounds__(128) void k4_fix(
    const float* att_seq, const float* hint_seq,
    const float* W_b1, const float* b_b1,
    const float* M_lnb, const float* fix_l, f16* PRE) {
  int b = blockIdx.x, j = threadIdx.x;
  int row = b * SS + (SS - 1);
  __shared__ float rb_s[128];
  float v = att_seq[row] * W_b1[j] + hint_seq[row] * W_b1[128 + j] + b_b1[j];
  rb_s[j] = fmaxf(v, 0.f);
  __syncthreads();
  float a = fix_l[j];
  for (int m = 0; m < 128; m++) a += rb_s[m] * M_lnb[m * 128 + j];
  PRE[row * 256 + j] = (f16)((float)PRE[row * 256 + j] - a);
}

// ---------------- K5: MFMA scan — 16 batch rows per block, 8 waves ----------------
// wave w owns output cols 16w..16w+15. h state kept f32 in C-layout registers.
// LDS holds h (double-buffered) and lg in A-fragment-readable, XOR-swizzled layout.
__global__ __launch_bounds__(512) void k5_scan_mfma(
    const f16* PRE, const f16* Wfrag, f16* h_hist) {
  __shared__ _Float16 Ah[2][16 * 128];   // 2 x 4KB
  __shared__ _Float16 Alg[16 * 128];     // 4KB
  int tid = threadIdx.x;
  int w = tid >> 6, lane = tid & 63;
  int c = lane & 15, g = lane >> 4;
  int b = blockIdx.x;

  // zero both h buffers (8KB total, 512 threads x 16B)
  ((float4*)&Ah[0][0])[tid] = make_float4(0.f, 0.f, 0.f, 0.f);

  // B-fragments (held in registers the whole scan)
  half8 bL[4], bFH[4], bFL[4];
  const half8* wp = (const half8*)Wfrag;
  #pragma unroll
  for (int t4 = 0; t4 < 4; t4++) {
    bL [t4] = wp[((0 * 8 + w) * 4 + t4) * 64 + lane];
    bFH[t4] = wp[((1 * 8 + w) * 4 + t4) * 64 + lane];
    bFL[t4] = wp[((2 * 8 + w) * 4 + t4) * 64 + lane];
  }
  int col = 16 * w + c;
  const f16* plp[4]; const f16* pfp[4]; f16* hhp[4];
  #pragma unroll
  for (int r = 0; r < 4; r++) {
    int br = b * 16 + g * 4 + r;
    plp[r] = PRE + (size_t)br * SS * 256 + col;
    pfp[r] = plp[r] + 128;
    hhp[r] = h_hist + (size_t)br * SS * 128 + col;
  }
  float hstate[4] = {0.f, 0.f, 0.f, 0.f};
  float preL[4], preF[4];
  #pragma unroll
  for (int r = 0; r < 4; r++) { preL[r] = (float)plp[r][0]; preF[r] = (float)pfp[r][0]; }
  __syncthreads();

  for (int t = 0; t < SS; t++) {
    int cur = t & 1, nxt = cur ^ 1;
    // A-frags of h: lane reads row=c, k = t4*32 + g*8 .. +7 (16B, swizzled)
    half8 ha[4];
    #pragma unroll
    for (int t4 = 0; t4 < 4; t4++) {
      int byte = c * 256 + t4 * 64 + g * 16; byte ^= ((c & 7) << 4);
      ha[t4] = *(const half8*)((const char*)&Ah[cur][0] + byte);
    }
    // prefetch next step's PRE
    f16 nl[4], nf[4];
    int tn = (t + 1 < SS) ? t + 1 : t;
    #pragma unroll
    for (int r = 0; r < 4; r++) {
      nl[r] = plp[r][(size_t)tn * 256];
      nf[r] = pfp[r][(size_t)tn * 256];
    }
    f32x4 accL = {0.f, 0.f, 0.f, 0.f}, accFH = {0.f, 0.f, 0.f, 0.f};
    #pragma unroll
    for (int t4 = 0; t4 < 4; t4++) {
      accL  = __builtin_amdgcn_mfma_f32_16x16x32_f16(ha[t4], bL[t4],  accL,  0, 0, 0);
      accFH = __builtin_amdgcn_mfma_f32_16x16x32_f16(ha[t4], bFH[t4], accFH, 0, 0, 0);
    }
    float lgf[4];
    #pragma unroll
    for (int r = 0; r < 4; r++) {
      lgf[r] = sigm(accL[r] + preL[r]);
      int m = g * 4 + r;
      int byte = m * 256 + col * 2; byte ^= ((m & 7) << 4);
      *(_Float16*)((char*)&Alg[0] + byte) = (_Float16)lgf[r];
    }
    __syncthreads();
    half8 la[4];
    #pragma unroll
    for (int t4 = 0; t4 < 4; t4++) {
      int byte = c * 256 + t4 * 64 + g * 16; byte ^= ((c & 7) << 4);
      la[t4] = *(const half8*)((const char*)&Alg[0] + byte);
    }
    f32x4 accFL = {0.f, 0.f, 0.f, 0.f};
    #pragma unroll
    for (int t4 = 0; t4 < 4; t4++)
      accFL = __builtin_amdgcn_mfma_f32_16x16x32_f16(la[t4], bFL[t4], accFL, 0, 0, 0);
    #pragma unroll
    for (int r = 0; r < 4; r++) {
      float fg = sigm(accFH[r] + accFL[r] + preF[r]);
      float hn = lgf[r] + fg * hstate[r];
      hstate[r] = hn;
      _Float16 hv = (_Float16)hn;
      int m = g * 4 + r;
      int byte = m * 256 + col * 2; byte ^= ((m & 7) << 4);
      *(_Float16*)((char*)&Ah[nxt][0] + byte) = hv;
      hhp[r][(size_t)t * 128] = hv;
      preL[r] = (float)nl[r]; preF[r] = (float)nf[r];
    }
    __syncthreads();
  }
}

// ---------------- K6: prediction dot-products ----------------
__global__ __launch_bounds__(256) void k6_pred(
    const f16* h_hist, const int* ex_seq, const float* ex_emb,
    const float* W_pred, const float* b_pred, float* out) {
  int tid = threadIdx.x;
  int w = tid >> 6, lane = tid & 63, sub = lane >> 5, li = lane & 31;
  int row = blockIdx.x * 8 + w * 2 + sub;
  int ex = ex_seq[row];
  const f16* hp = h_hist + (size_t)row * 128 + li * 4;
  const float* ep = ex_emb + (size_t)ex * 128 + li * 4;
  float s = 0.f;
  #pragma unroll
  for (int q = 0; q < 4; q++) {
    int d = li * 4 + q;
    s += (float)hp[q] * W_pred[d];
    s += ep[q] * W_pred[128 + d];
  }
  #pragma unroll
  for (int m = 1; m < 32; m <<= 1) s += __shfl_xor(s, m, 64);
  if (li == 0) out[row] = sigm(s + b_pred[0]);
}

extern "C" void kernel_launch(void* const* d_in, const int* in_sizes, int n_in,
                              void* d_out, int out_size, void* d_ws, size_t ws_size,
                              hipStream_t stream) {
  const int*   ex_seq   = (const int*)d_in[0];
  const int*   sk_seq   = (const int*)d_in[1];
  const int*   re_seq   = (const int*)d_in[2];
  const float* time_seq = (const float*)d_in[3];
  const float* interval_seq = (const float*)d_in[4];
  const float* att_seq  = (const float*)d_in[5];
  const float* hint_seq = (const float*)d_in[6];
  // d_in[7] q_matrix: unused
  const float* ex_emb   = (const float*)d_in[8];
  const float* sk_emb   = (const float*)d_in[9];
  const float* re_emb   = (const float*)d_in[10];
  const float* W_time   = (const float*)d_in[11];
  const float* b_time   = (const float*)d_in[12];
  const float* W_int    = (const float*)d_in[13];
  const float* b_int    = (const float*)d_in[14];
  const float* W_b1     = (const float*)d_in[15];
  const float* b_b1     = (const float*)d_in[16];
  const float* W_b2     = (const float*)d_in[17];
  const float* b_b2     = (const float*)d_in[18];
  const float* W_learn  = (const float*)d_in[19];
  const float* b_learn  = (const float*)d_in[20];
  const float* W_forget = (const float*)d_in[21];
  const float* b_forget = (const float*)d_in[22];
  const float* W_pred   = (const float*)d_in[23];
  const float* b_pred   = (const float*)d_in[24];

  char* ws = (char*)d_ws;
  float* Ee    = (float*)(ws);              // 10,240,000
  float* Se    = (float*)(ws + 10240000);
  float* Re    = (float*)(ws + 10496000);
  float* Te    = (float*)(ws + 10497024);
  float* cbias = (float*)(ws + 10497536);
  float* c_lg  = (float*)(ws + 10498048);
  float* c_fg  = (float*)(ws + 10498560);
  float* fix_l = (float*)(ws + 10499072);
  float* Wcat  = (float*)(ws + 10499584);   // 262,144
  float* M_lnb = (float*)(ws + 10761728);   // 65,536
  f16*   PRE   = (f16*)  (ws + 10827264);   // 67,108,864
  f16*   h_hist= (f16*)  (ws + 77936128);   // 33,554,432
  f16*   Wfrag = (f16*)  (ws + 111490560);  // 98,304  -> total 111,588,864

  k0_folds<<<dim3(888), dim3(128), 0, stream>>>(
      sk_emb, re_emb, W_time, b_time, W_int, b_int, W_b2, b_b2,
      W_learn, b_learn, W_forget, b_forget,
      Se, Re, Te, cbias, c_lg, c_fg, fix_l, Wcat, M_lnb);
  k1_Ee<<<dim3(2500), dim3(256), 0, stream>>>(ex_emb, W_int, Ee);
  k2_wprep<<<dim3(96), dim3(64), 0, stream>>>(W_learn, W_forget, Wfrag);
  k3_gemm<<<dim3(4096), dim3(256), 0, stream>>>(
      ex_seq, sk_seq, re_seq, time_seq, interval_seq, att_seq, hint_seq,
      W_b1, b_b1, W_learn, Ee, Se, Re, Te, cbias, c_lg, c_fg, Wcat, PRE);
  k4_fix<<<dim3(256), dim3(128), 0, stream>>>(
      att_seq, hint_seq, W_b1, b_b1, M_lnb, fix_l, PRE);
  k5_scan_mfma<<<dim3(16), dim3(512), 0, stream>>>(PRE, Wfrag, h_hist);
  k6_pred<<<dim3(16384), dim3(256), 0, stream>>>(
      h_hist, ex_seq, ex_emb, W_pred, b_pred, (float*)d_out);
}

// Round 3
// 614.391 us; speedup vs baseline: 1.7615x; 1.7054x over previous
//
#include <hip/hip_runtime.h>
#include <hip/hip_fp16.h>

#define BB 256
#define SS 512
#define EE_N 20000
typedef _Float16 f16;
typedef __attribute__((ext_vector_type(8))) _Float16 half8;
typedef __attribute__((ext_vector_type(4))) float f32x4;

__device__ __forceinline__ float sigm(float x) { return 1.0f / (1.0f + __expf(-x)); }

// ---------------- K0: small folds ----------------
__global__ __launch_bounds__(128) void k0_folds(
    const float* skill_emb, const float* response_emb,
    const float* W_time, const float* b_time,
    const float* W_int, const float* b_int,
    const float* W_b2, const float* b_b2,
    const float* W_learn, const float* b_learn,
    const float* W_forget, const float* b_forget,
    float* Se, float* Re, float* Te, float* cbias,
    float* c_lg, float* c_fg, float* fix_l,
    float* Wcat, float* M_lnb) {
  int blk = blockIdx.x, j = threadIdx.x;
  if (blk < 500) {
    float a = 0.f;
    for (int k = 0; k < 128; k++) a += skill_emb[blk * 128 + k] * W_int[(128 + k) * 128 + j];
    Se[blk * 128 + j] = a;
  } else if (blk < 502) {
    int i = blk - 500; float a = 0.f;
    for (int k = 0; k < 128; k++) a += response_emb[i * 128 + k] * W_int[(384 + k) * 128 + j];
    Re[i * 128 + j] = a;
  } else if (blk == 502) {
    float a = 0.f, c = 0.f;
    for (int k = 0; k < 128; k++) {
      float w = W_int[(256 + k) * 128 + j];
      a += W_time[k] * w; c += b_time[k] * w;
    }
    Te[j] = a; cbias[j] = b_int[j] + c;
  } else if (blk < 503 + 128) {
    int k = blk - 503;
    Wcat[k * 256 + j]       = W_learn[(128 + k) * 128 + j];
    Wcat[k * 256 + 128 + j] = W_forget[(128 + k) * 128 + j];
  } else if (blk < 631 + 128) {
    int k = blk - 631; float a = 0.f, c = 0.f;
    for (int m = 0; m < 128; m++) {
      float w = W_b2[k * 128 + m];
      a += w * (W_learn[(257 + m) * 128 + j] + W_learn[(385 + m) * 128 + j]);
      c += w * W_forget[(384 + m) * 128 + j];
    }
    Wcat[(128 + k) * 256 + j] = a;
    Wcat[(128 + k) * 256 + 128 + j] = c;
  } else if (blk < 759 + 128) {
    int k = blk - 759; float a = 0.f;
    for (int m = 0; m < 128; m++) a += W_b2[k * 128 + m] * W_learn[(385 + m) * 128 + j];
    M_lnb[k * 128 + j] = a;
  } else {
    float a = 0.f, c = 0.f, f = 0.f;
    for (int m = 0; m < 128; m++) {
      float w = b_b2[m];
      a += w * (W_learn[(257 + m) * 128 + j] + W_learn[(385 + m) * 128 + j]);
      c += w * W_forget[(384 + m) * 128 + j];
      f += w * W_learn[(385 + m) * 128 + j];
    }
    c_lg[j] = b_learn[j] + a;
    c_fg[j] = b_forget[j] + c;
    fix_l[j] = f;
  }
}

// ---------------- K1: Ee = exercise_emb @ W_int[0:128,:] ----------------
__global__ __launch_bounds__(256) void k1_Ee(const float* ex_emb, const float* W_int, float* Ee) {
  __shared__ float es[8 * 128];
  int tid = threadIdx.x, blk = blockIdx.x;
  *(float4*)&es[tid * 4] = *(const float4*)&ex_emb[blk * 1024 + tid * 4];
  __syncthreads();
  int d = tid & 127, rg = tid >> 7;
  float a0 = 0, a1 = 0, a2 = 0, a3 = 0;
  for (int k = 0; k < 128; k++) {
    float w = W_int[k * 128 + d];
    a0 += es[(rg * 4 + 0) * 128 + k] * w;
    a1 += es[(rg * 4 + 1) * 128 + k] * w;
    a2 += es[(rg * 4 + 2) * 128 + k] * w;
    a3 += es[(rg * 4 + 3) * 128 + k] * w;
  }
  Ee[(blk * 8 + rg * 4 + 0) * 128 + d] = a0;
  Ee[(blk * 8 + rg * 4 + 1) * 128 + d] = a1;
  Ee[(blk * 8 + rg * 4 + 2) * 128 + d] = a2;
  Ee[(blk * 8 + rg * 4 + 3) * 128 + d] = a3;
}

// ---------------- K1b: pe[e] = ex_emb[e] . W_pred[128:256] ----------------
__global__ __launch_bounds__(256) void k1b_pe(const float* ex_emb, const float* W_pred, float* pe) {
  int tid = threadIdx.x;
  int w = tid >> 6, l = tid & 63, g = l >> 4, li = l & 15;
  int row = blockIdx.x * 16 + w * 4 + g;
  const float4* ep = (const float4*)(ex_emb + (size_t)row * 128 + li * 8);
  const float4* wp = (const float4*)(W_pred + 128 + li * 8);
  float4 e0 = ep[0], e1 = ep[1], w0 = wp[0], w1 = wp[1];
  float s = e0.x * w0.x + e0.y * w0.y + e0.z * w0.z + e0.w * w0.w
          + e1.x * w1.x + e1.y * w1.y + e1.z * w1.z + e1.w * w1.w;
  #pragma unroll
  for (int m = 1; m < 16; m <<= 1) s += __shfl_xor(s, m);
  if (li == 0) pe[row] = s;
}

// ---------------- K2: scan weights -> MFMA B-fragment layout (f16) ----------------
__global__ __launch_bounds__(64) void k2_wprep(const float* W_learn, const float* W_forget, f16* Wfrag) {
  int blk = blockIdx.x;               // 0..95 = (mat*8 + w)*4 + t4
  int mat = blk >> 5, rem = blk & 31, w = rem >> 2, t4 = rem & 3;
  int lane = threadIdx.x;
  int cc = lane & 15, gg = lane >> 4;
  const float* src = (mat == 0) ? W_learn : (mat == 1 ? W_forget : W_forget + 256 * 128);
  f16* dst = Wfrag + ((size_t)blk * 64 + lane) * 8;
  #pragma unroll
  for (int e = 0; e < 8; e++) {
    int k = t4 * 32 + gg * 8 + e;
    int j = 16 * w + cc;
    dst[e] = (f16)src[k * 128 + j];
  }
}

// ---------------- K2b: Wcat -> MFMA B-fragment layout (f16) ----------------
// Bfrag[(nct*8 + kt)*64 + lane][e] = Wcat[kt*32 + (lane>>4)*8 + e][nct*16 + (lane&15)]
__global__ __launch_bounds__(64) void k2b_bprep(const float* Wcat, f16* Bfrag) {
  int blk = blockIdx.x;               // 0..127 = nct*8 + kt
  int nct = blk >> 3, kt = blk & 7;
  int lane = threadIdx.x;
  int cc = lane & 15, gg = lane >> 4;
  f16* dst = Bfrag + ((size_t)blk * 64 + lane) * 8;
  #pragma unroll
  for (int e = 0; e < 8; e++) {
    int k = kt * 32 + gg * 8 + e;
    dst[e] = (f16)Wcat[k * 256 + nct * 16 + cc];
  }
}

// ---------------- K3: fused pre-activation GEMM via MFMA ----------------
// 64 rows/block, N=256, K=256. 8 waves; wave w owns cols 32w..32w+31.
__global__ __launch_bounds__(512) void k3_gemm_mfma(
    const int* ex_seq, const int* sk_seq, const int* re_seq,
    const float* time_seq, const float* interval_seq,
    const float* att_seq, const float* hint_seq,
    const float* W_b1, const float* b_b1,
    const float* Wiv,                      // = W_learn + 256*128
    const float* Ee, const float* Se, const float* Re,
    const float* Te, const float* cbias,
    const float* c_lg, const float* c_fg,
    const f16* Bfrag, f16* PRE) {
  __shared__ _Float16 Ah[64 * 256];   // 32KB, XOR-swizzled
  __shared__ float ivs[64];
  int tid = threadIdx.x;
  int w = tid >> 6, lane = tid & 63;
  int c = lane & 15, g = lane >> 4;
  int rowbase = blockIdx.x * 64;

  // B fragments: 2 col-tiles x 8 K-steps, from global (L2-resident)
  half8 bfr[2][8];
  const half8* bp = (const half8*)Bfrag;
  #pragma unroll
  for (int ncl = 0; ncl < 2; ncl++)
    #pragma unroll
    for (int kt = 0; kt < 8; kt++)
      bfr[ncl][kt] = bp[((size_t)((w * 2 + ncl) * 8 + kt)) * 64 + lane];

  // ---- stage A ----
  {
    int r = tid & 63, seg = tid >> 6;   // seg 0..7
    int row = rowbase + r;
    if (seg == 0) ivs[r] = interval_seq[row];
    char* ab = (char*)Ah;
    if (seg < 4) {
      int ex = ex_seq[row], sk = sk_seq[row], rp = re_seq[row];
      float tm = time_seq[row];
      const float4* ee = (const float4*)(Ee + (size_t)ex * 128 + seg * 32);
      const float4* se = (const float4*)(Se + (size_t)sk * 128 + seg * 32);
      const float4* re = (const float4*)(Re + (size_t)rp * 128 + seg * 32);
      const float4* te = (const float4*)(Te + seg * 32);
      const float4* cb = (const float4*)(cbias + seg * 32);
      #pragma unroll
      for (int i8 = 0; i8 < 4; i8++) {
        half8 hv;
        #pragma unroll
        for (int q = 0; q < 2; q++) {
          float4 e4 = ee[i8 * 2 + q], s4 = se[i8 * 2 + q], r4 = re[i8 * 2 + q];
          float4 t4 = te[i8 * 2 + q], c4 = cb[i8 * 2 + q];
          hv[q * 4 + 0] = (_Float16)fmaxf(e4.x + s4.x + tm * t4.x + r4.x + c4.x, 0.f);
          hv[q * 4 + 1] = (_Float16)fmaxf(e4.y + s4.y + tm * t4.y + r4.y + c4.y, 0.f);
          hv[q * 4 + 2] = (_Float16)fmaxf(e4.z + s4.z + tm * t4.z + r4.z + c4.z, 0.f);
          hv[q * 4 + 3] = (_Float16)fmaxf(e4.w + s4.w + tm * t4.w + r4.w + c4.w, 0.f);
        }
        int k0 = seg * 32 + i8 * 8;
        int byte = r * 512 + k0 * 2; byte ^= ((r & 7) << 4);
        *(half8*)(ab + byte) = hv;
      }
    } else {
      int k2b_ = (seg - 4) * 32;
      float at = att_seq[row], hi = hint_seq[row];
      const float4* wa = (const float4*)(W_b1 + k2b_);
      const float4* wh = (const float4*)(W_b1 + 128 + k2b_);
      const float4* bb = (const float4*)(b_b1 + k2b_);
      #pragma unroll
      for (int i8 = 0; i8 < 4; i8++) {
        half8 hv;
        #pragma unroll
        for (int q = 0; q < 2; q++) {
          float4 a4 = wa[i8 * 2 + q], h4 = wh[i8 * 2 + q], b4 = bb[i8 * 2 + q];
          hv[q * 4 + 0] = (_Float16)fmaxf(at * a4.x + hi * h4.x + b4.x, 0.f);
          hv[q * 4 + 1] = (_Float16)fmaxf(at * a4.y + hi * h4.y + b4.y, 0.f);
          hv[q * 4 + 2] = (_Float16)fmaxf(at * a4.z + hi * h4.z + b4.z, 0.f);
          hv[q * 4 + 3] = (_Float16)fmaxf(at * a4.w + hi * h4.w + b4.w, 0.f);
        }
        int k0 = 128 + k2b_ + i8 * 8;
        int byte = r * 512 + k0 * 2; byte ^= ((r & 7) << 4);
        *(half8*)(ab + byte) = hv;
      }
    }
  }
  __syncthreads();

  // ---- MFMA: acc[mr][ncl], mr row-tiles 0..3, ncl col-tiles 0..1 ----
  f32x4 acc[4][2] = {};
  const char* ab = (const char*)Ah;
  #pragma unroll
  for (int kt = 0; kt < 8; kt++) {
    #pragma unroll
    for (int mr = 0; mr < 4; mr++) {
      int byte = (mr * 16 + c) * 512 + kt * 64 + g * 16; byte ^= ((c & 7) << 4);
      half8 a = *(const half8*)(ab + byte);
      acc[mr][0] = __builtin_amdgcn_mfma_f32_16x16x32_f16(a, bfr[0][kt], acc[mr][0], 0, 0, 0);
      acc[mr][1] = __builtin_amdgcn_mfma_f32_16x16x32_f16(a, bfr[1][kt], acc[mr][1], 0, 0, 0);
    }
  }

  // ---- epilogue ----
  bool isL = (w < 4);
  float addc[2], wiv[2];
  #pragma unroll
  for (int ncl = 0; ncl < 2; ncl++) {
    int j = w * 32 + ncl * 16 + c;
    if (isL) { addc[ncl] = c_lg[j]; wiv[ncl] = Wiv[j]; }
    else     { addc[ncl] = c_fg[j - 128]; wiv[ncl] = 0.f; }
  }
  #pragma unroll
  for (int mr = 0; mr < 4; mr++) {
    #pragma unroll
    for (int rr = 0; rr < 4; rr++) {
      int rl = mr * 16 + g * 4 + rr;
      int row = rowbase + rl;
      float iv = ivs[rl];
      #pragma unroll
      for (int ncl = 0; ncl < 2; ncl++) {
        float v = acc[mr][ncl][rr] + addc[ncl] + iv * wiv[ncl];
        PRE[(size_t)row * 256 + w * 32 + ncl * 16 + c] = (f16)v;
      }
    }
  }
}

// ---------------- K4: last-step nb fixup ----------------
__global__ __launch_bounds__(128) void k4_fix(
    const float* att_seq, const float* hint_seq,
    const float* W_b1, const float* b_b1,
    const float* M_lnb, const float* fix_l, f16* PRE) {
  int b = blockIdx.x, j = threadIdx.x;
  int row = b * SS + (SS - 1);
  __shared__ float rb_s[128];
  float v = att_seq[row] * W_b1[j] + hint_seq[row] * W_b1[128 + j] + b_b1[j];
  rb_s[j] = fmaxf(v, 0.f);
  __syncthreads();
  float a = fix_l[j];
  for (int m = 0; m < 128; m++) a += rb_s[m] * M_lnb[m * 128 + j];
  PRE[row * 256 + j] = (f16)((float)PRE[row * 256 + j] - a);
}

// ---------------- K5: MFMA scan — 16 batch rows per block, 8 waves ----------------
__global__ __launch_bounds__(512) void k5_scan_mfma(
    const f16* PRE, const f16* Wfrag, f16* h_hist) {
  __shared__ _Float16 Ah[2][16 * 128];
  __shared__ _Float16 Alg[16 * 128];
  int tid = threadIdx.x;
  int w = tid >> 6, lane = tid & 63;
  int c = lane & 15, g = lane >> 4;
  int b = blockIdx.x;

  ((float4*)&Ah[0][0])[tid] = make_float4(0.f, 0.f, 0.f, 0.f);

  half8 bL[4], bFH[4], bFL[4];
  const half8* wp = (const half8*)Wfrag;
  #pragma unroll
  for (int t4 = 0; t4 < 4; t4++) {
    bL [t4] = wp[((0 * 8 + w) * 4 + t4) * 64 + lane];
    bFH[t4] = wp[((1 * 8 + w) * 4 + t4) * 64 + lane];
    bFL[t4] = wp[((2 * 8 + w) * 4 + t4) * 64 + lane];
  }
  int col = 16 * w + c;
  const f16* plp[4]; const f16* pfp[4]; f16* hhp[4];
  #pragma unroll
  for (int r = 0; r < 4; r++) {
    int br = b * 16 + g * 4 + r;
    plp[r] = PRE + (size_t)br * SS * 256 + col;
    pfp[r] = plp[r] + 128;
    hhp[r] = h_hist + (size_t)br * SS * 128 + col;
  }
  float hstate[4] = {0.f, 0.f, 0.f, 0.f};
  float preL[4], preF[4];
  #pragma unroll
  for (int r = 0; r < 4; r++) { preL[r] = (float)plp[r][0]; preF[r] = (float)pfp[r][0]; }
  __syncthreads();

  for (int t = 0; t < SS; t++) {
    int cur = t & 1, nxt = cur ^ 1;
    half8 ha[4];
    #pragma unroll
    for (int t4 = 0; t4 < 4; t4++) {
      int byte = c * 256 + t4 * 64 + g * 16; byte ^= ((c & 7) << 4);
      ha[t4] = *(const half8*)((const char*)&Ah[cur][0] + byte);
    }
    f16 nl[4], nf[4];
    int tn = (t + 1 < SS) ? t + 1 : t;
    #pragma unroll
    for (int r = 0; r < 4; r++) {
      nl[r] = plp[r][(size_t)tn * 256];
      nf[r] = pfp[r][(size_t)tn * 256];
    }
    f32x4 accL = {0.f, 0.f, 0.f, 0.f}, accFH = {0.f, 0.f, 0.f, 0.f};
    #pragma unroll
    for (int t4 = 0; t4 < 4; t4++) {
      accL  = __builtin_amdgcn_mfma_f32_16x16x32_f16(ha[t4], bL[t4],  accL,  0, 0, 0);
      accFH = __builtin_amdgcn_mfma_f32_16x16x32_f16(ha[t4], bFH[t4], accFH, 0, 0, 0);
    }
    float lgf[4];
    #pragma unroll
    for (int r = 0; r < 4; r++) {
      lgf[r] = sigm(accL[r] + preL[r]);
      int m = g * 4 + r;
      int byte = m * 256 + col * 2; byte ^= ((m & 7) << 4);
      *(_Float16*)((char*)&Alg[0] + byte) = (_Float16)lgf[r];
    }
    __syncthreads();
    half8 la[4];
    #pragma unroll
    for (int t4 = 0; t4 < 4; t4++) {
      int byte = c * 256 + t4 * 64 + g * 16; byte ^= ((c & 7) << 4);
      la[t4] = *(const half8*)((const char*)&Alg[0] + byte);
    }
    f32x4 accFL = {0.f, 0.f, 0.f, 0.f};
    #pragma unroll
    for (int t4 = 0; t4 < 4; t4++)
      accFL = __builtin_amdgcn_mfma_f32_16x16x32_f16(la[t4], bFL[t4], accFL, 0, 0, 0);
    #pragma unroll
    for (int r = 0; r < 4; r++) {
      float fg = sigm(accFH[r] + accFL[r] + preF[r]);
      float hn = lgf[r] + fg * hstate[r];
      hstate[r] = hn;
      _Float16 hv = (_Float16)hn;
      int m = g * 4 + r;
      int byte = m * 256 + col * 2; byte ^= ((m & 7) << 4);
      *(_Float16*)((char*)&Ah[nxt][0] + byte) = hv;
      hhp[r][(size_t)t * 128] = hv;
      preL[r] = (float)nl[r]; preF[r] = (float)nf[r];
    }
    __syncthreads();
  }
}

// ---------------- K6: prediction dot-products ----------------
__global__ __launch_bounds__(256) void k6_pred(
    const f16* h_hist, const int* ex_seq, const float* pe,
    const float* W_pred, const float* b_pred, float* out) {
  int tid = threadIdx.x;
  int w = tid >> 6, l = tid & 63, g = l >> 4, li = l & 15;
  int row = blockIdx.x * 16 + w * 4 + g;
  half8 h8 = *(const half8*)(h_hist + (size_t)row * 128 + li * 8);
  const float4* wp = (const float4*)(W_pred + li * 8);
  float4 w0 = wp[0], w1 = wp[1];
  float s = (float)h8[0] * w0.x + (float)h8[1] * w0.y + (float)h8[2] * w0.z + (float)h8[3] * w0.w
          + (float)h8[4] * w1.x + (float)h8[5] * w1.y + (float)h8[6] * w1.z + (float)h8[7] * w1.w;
  #pragma unroll
  for (int m = 1; m < 16; m <<= 1) s += __shfl_xor(s, m);
  if (li == 0) out[row] = sigm(s + pe[ex_seq[row]] + b_pred[0]);
}

extern "C" void kernel_launch(void* const* d_in, const int* in_sizes, int n_in,
                              void* d_out, int out_size, void* d_ws, size_t ws_size,
                              hipStream_t stream) {
  const int*   ex_seq   = (const int*)d_in[0];
  const int*   sk_seq   = (const int*)d_in[1];
  const int*   re_seq   = (const int*)d_in[2];
  const float* time_seq = (const float*)d_in[3];
  const float* interval_seq = (const float*)d_in[4];
  const float* att_seq  = (const float*)d_in[5];
  const float* hint_seq = (const float*)d_in[6];
  // d_in[7] q_matrix: unused
  const float* ex_emb   = (const float*)d_in[8];
  const float* sk_emb   = (const float*)d_in[9];
  const float* re_emb   = (const float*)d_in[10];
  const float* W_time   = (const float*)d_in[11];
  const float* b_time   = (const float*)d_in[12];
  const float* W_int    = (const float*)d_in[13];
  const float* b_int    = (const float*)d_in[14];
  const float* W_b1     = (const float*)d_in[15];
  const float* b_b1     = (const float*)d_in[16];
  const float* W_b2     = (const float*)d_in[17];
  const float* b_b2     = (const float*)d_in[18];
  const float* W_learn  = (const float*)d_in[19];
  const float* b_learn  = (const float*)d_in[20];
  const float* W_forget = (const float*)d_in[21];
  const float* b_forget = (const float*)d_in[22];
  const float* W_pred   = (const float*)d_in[23];
  const float* b_pred   = (const float*)d_in[24];

  char* ws = (char*)d_ws;
  float* Ee    = (float*)(ws);              // 10,240,000
  float* Se    = (float*)(ws + 10240000);
  float* Re    = (float*)(ws + 10496000);
  float* Te    = (float*)(ws + 10497024);
  float* cbias = (float*)(ws + 10497536);
  float* c_lg  = (float*)(ws + 10498048);
  float* c_fg  = (float*)(ws + 10498560);
  float* fix_l = (float*)(ws + 10499072);
  float* Wcat  = (float*)(ws + 10499584);   // 262,144
  float* M_lnb = (float*)(ws + 10761728);   // 65,536
  f16*   PRE   = (f16*)  (ws + 10827264);   // 67,108,864
  f16*   h_hist= (f16*)  (ws + 77936128);   // 33,554,432
  f16*   Wfrag = (f16*)  (ws + 111490560);  // 98,304  -> total 111,588,864
  // aliased scratch (regions dead at use time):
  f16*   Bfrag = (f16*)  (ws + 77936128);   // aliases h_hist head (dead until k5 writes it)
  float* pe    = (float*)(ws + 10499584);   // aliases Wcat (dead after k2b)

  k0_folds<<<dim3(888), dim3(128), 0, stream>>>(
      sk_emb, re_emb, W_time, b_time, W_int, b_int, W_b2, b_b2,
      W_learn, b_learn, W_forget, b_forget,
      Se, Re, Te, cbias, c_lg, c_fg, fix_l, Wcat, M_lnb);
  k1_Ee<<<dim3(2500), dim3(256), 0, stream>>>(ex_emb, W_int, Ee);
  k2_wprep<<<dim3(96), dim3(64), 0, stream>>>(W_learn, W_forget, Wfrag);
  k2b_bprep<<<dim3(128), dim3(64), 0, stream>>>(Wcat, Bfrag);
  k1b_pe<<<dim3(1250), dim3(256), 0, stream>>>(ex_emb, W_pred, pe);  // overwrites Wcat (done)
  k3_gemm_mfma<<<dim3(2048), dim3(512), 0, stream>>>(
      ex_seq, sk_seq, re_seq, time_seq, interval_seq, att_seq, hint_seq,
      W_b1, b_b1, W_learn + 256 * 128, Ee, Se, Re, Te, cbias, c_lg, c_fg, Bfrag, PRE);
  k4_fix<<<dim3(256), dim3(128), 0, stream>>>(
      att_seq, hint_seq, W_b1, b_b1, M_lnb, fix_l, PRE);
  k5_scan_mfma<<<dim3(16), dim3(512), 0, stream>>>(PRE, Wfrag, h_hist);
  k6_pred<<<dim3(8192), dim3(256), 0, stream>>>(
      h_hist, ex_seq, pe, W_pred, b_pred, (float*)d_out);
}

// Round 4
// 576.008 us; speedup vs baseline: 1.8788x; 1.0666x over previous
//
#include <hip/hip_runtime.h>
#include <hip/hip_fp16.h>

#define BB 256
#define SS 512
#define EE_N 20000
typedef _Float16 f16;
typedef __attribute__((ext_vector_type(8))) _Float16 half8;
typedef __attribute__((ext_vector_type(4))) float f32x4;

__device__ __forceinline__ float sigm(float x) { return 1.0f / (1.0f + __expf(-x)); }

// ---------------- K0: small folds ----------------
__global__ __launch_bounds__(128) void k0_folds(
    const float* skill_emb, const float* response_emb,
    const float* W_time, const float* b_time,
    const float* W_int, const float* b_int,
    const float* W_b2, const float* b_b2,
    const float* W_learn, const float* b_learn,
    const float* W_forget, const float* b_forget,
    float* Se, float* Re, float* Te, float* cbias,
    float* c_lg, float* c_fg, float* fix_l,
    float* Wcat, float* M_lnb) {
  int blk = blockIdx.x, j = threadIdx.x;
  if (blk < 500) {
    float a = 0.f;
    for (int k = 0; k < 128; k++) a += skill_emb[blk * 128 + k] * W_int[(128 + k) * 128 + j];
    Se[blk * 128 + j] = a;
  } else if (blk < 502) {
    int i = blk - 500; float a = 0.f;
    for (int k = 0; k < 128; k++) a += response_emb[i * 128 + k] * W_int[(384 + k) * 128 + j];
    Re[i * 128 + j] = a;
  } else if (blk == 502) {
    float a = 0.f, c = 0.f;
    for (int k = 0; k < 128; k++) {
      float w = W_int[(256 + k) * 128 + j];
      a += W_time[k] * w; c += b_time[k] * w;
    }
    Te[j] = a; cbias[j] = b_int[j] + c;
  } else if (blk < 503 + 128) {
    int k = blk - 503;
    Wcat[k * 256 + j]       = W_learn[(128 + k) * 128 + j];
    Wcat[k * 256 + 128 + j] = W_forget[(128 + k) * 128 + j];
  } else if (blk < 631 + 128) {
    int k = blk - 631; float a = 0.f, c = 0.f;
    for (int m = 0; m < 128; m++) {
      float w = W_b2[k * 128 + m];
      a += w * (W_learn[(257 + m) * 128 + j] + W_learn[(385 + m) * 128 + j]);
      c += w * W_forget[(384 + m) * 128 + j];
    }
    Wcat[(128 + k) * 256 + j] = a;
    Wcat[(128 + k) * 256 + 128 + j] = c;
  } else if (blk < 759 + 128) {
    int k = blk - 759; float a = 0.f;
    for (int m = 0; m < 128; m++) a += W_b2[k * 128 + m] * W_learn[(385 + m) * 128 + j];
    M_lnb[k * 128 + j] = a;
  } else {
    float a = 0.f, c = 0.f, f = 0.f;
    for (int m = 0; m < 128; m++) {
      float w = b_b2[m];
      a += w * (W_learn[(257 + m) * 128 + j] + W_learn[(385 + m) * 128 + j]);
      c += w * W_forget[(384 + m) * 128 + j];
      f += w * W_learn[(385 + m) * 128 + j];
    }
    c_lg[j] = b_learn[j] + a;
    c_fg[j] = b_forget[j] + c;
    fix_l[j] = f;
  }
}

// ---------------- K1: Ee = exercise_emb @ W_int[0:128,:] ----------------
__global__ __launch_bounds__(256) void k1_Ee(const float* ex_emb, const float* W_int, float* Ee) {
  __shared__ float es[8 * 128];
  int tid = threadIdx.x, blk = blockIdx.x;
  *(float4*)&es[tid * 4] = *(const float4*)&ex_emb[blk * 1024 + tid * 4];
  __syncthreads();
  int d = tid & 127, rg = tid >> 7;
  float a0 = 0, a1 = 0, a2 = 0, a3 = 0;
  for (int k = 0; k < 128; k++) {
    float w = W_int[k * 128 + d];
    a0 += es[(rg * 4 + 0) * 128 + k] * w;
    a1 += es[(rg * 4 + 1) * 128 + k] * w;
    a2 += es[(rg * 4 + 2) * 128 + k] * w;
    a3 += es[(rg * 4 + 3) * 128 + k] * w;
  }
  Ee[(blk * 8 + rg * 4 + 0) * 128 + d] = a0;
  Ee[(blk * 8 + rg * 4 + 1) * 128 + d] = a1;
  Ee[(blk * 8 + rg * 4 + 2) * 128 + d] = a2;
  Ee[(blk * 8 + rg * 4 + 3) * 128 + d] = a3;
}

// ---------------- K1b: pe[e] = ex_emb[e] . W_pred[128:256] ----------------
__global__ __launch_bounds__(256) void k1b_pe(const float* ex_emb, const float* W_pred, float* pe) {
  int tid = threadIdx.x;
  int w = tid >> 6, l = tid & 63, g = l >> 4, li = l & 15;
  int row = blockIdx.x * 16 + w * 4 + g;
  const float4* ep = (const float4*)(ex_emb + (size_t)row * 128 + li * 8);
  const float4* wp = (const float4*)(W_pred + 128 + li * 8);
  float4 e0 = ep[0], e1 = ep[1], w0 = wp[0], w1 = wp[1];
  float s = e0.x * w0.x + e0.y * w0.y + e0.z * w0.z + e0.w * w0.w
          + e1.x * w1.x + e1.y * w1.y + e1.z * w1.z + e1.w * w1.w;
  #pragma unroll
  for (int m = 1; m < 16; m <<= 1) s += __shfl_xor(s, m);
  if (li == 0) pe[row] = s;
}

// ---------------- K2: scan weights -> MFMA B-fragment layout (f16) ----------------
__global__ __launch_bounds__(64) void k2_wprep(const float* W_learn, const float* W_forget, f16* Wfrag) {
  int blk = blockIdx.x;               // 0..95 = (mat*8 + w)*4 + t4
  int mat = blk >> 5, rem = blk & 31, w = rem >> 2, t4 = rem & 3;
  int lane = threadIdx.x;
  int cc = lane & 15, gg = lane >> 4;
  const float* src = (mat == 0) ? W_learn : (mat == 1 ? W_forget : W_forget + 256 * 128);
  f16* dst = Wfrag + ((size_t)blk * 64 + lane) * 8;
  #pragma unroll
  for (int e = 0; e < 8; e++) {
    int k = t4 * 32 + gg * 8 + e;
    int j = 16 * w + cc;
    dst[e] = (f16)src[k * 128 + j];
  }
}

// ---------------- K2b: Wcat -> MFMA B-fragment layout (f16) ----------------
__global__ __launch_bounds__(64) void k2b_bprep(const float* Wcat, f16* Bfrag) {
  int blk = blockIdx.x;               // 0..127 = nct*8 + kt
  int nct = blk >> 3, kt = blk & 7;
  int lane = threadIdx.x;
  int cc = lane & 15, gg = lane >> 4;
  f16* dst = Bfrag + ((size_t)blk * 64 + lane) * 8;
  #pragma unroll
  for (int e = 0; e < 8; e++) {
    int k = kt * 32 + gg * 8 + e;
    dst[e] = (f16)Wcat[k * 256 + nct * 16 + cc];
  }
}

// ---------------- K3: fused pre-activation GEMM via MFMA ----------------
__global__ __launch_bounds__(512) void k3_gemm_mfma(
    const int* ex_seq, const int* sk_seq, const int* re_seq,
    const float* time_seq, const float* interval_seq,
    const float* att_seq, const float* hint_seq,
    const float* W_b1, const float* b_b1,
    const float* Wiv,
    const float* Ee, const float* Se, const float* Re,
    const float* Te, const float* cbias,
    const float* c_lg, const float* c_fg,
    const f16* Bfrag, f16* PRE) {
  __shared__ _Float16 Ah[64 * 256];
  __shared__ float ivs[64];
  int tid = threadIdx.x;
  int w = tid >> 6, lane = tid & 63;
  int c = lane & 15, g = lane >> 4;
  int rowbase = blockIdx.x * 64;

  half8 bfr[2][8];
  const half8* bp = (const half8*)Bfrag;
  #pragma unroll
  for (int ncl = 0; ncl < 2; ncl++)
    #pragma unroll
    for (int kt = 0; kt < 8; kt++)
      bfr[ncl][kt] = bp[((size_t)((w * 2 + ncl) * 8 + kt)) * 64 + lane];

  {
    int r = tid & 63, seg = tid >> 6;
    int row = rowbase + r;
    if (seg == 0) ivs[r] = interval_seq[row];
    char* ab = (char*)Ah;
    if (seg < 4) {
      int ex = ex_seq[row], sk = sk_seq[row], rp = re_seq[row];
      float tm = time_seq[row];
      const float4* ee = (const float4*)(Ee + (size_t)ex * 128 + seg * 32);
      const float4* se = (const float4*)(Se + (size_t)sk * 128 + seg * 32);
      const float4* re = (const float4*)(Re + (size_t)rp * 128 + seg * 32);
      const float4* te = (const float4*)(Te + seg * 32);
      const float4* cb = (const float4*)(cbias + seg * 32);
      #pragma unroll
      for (int i8 = 0; i8 < 4; i8++) {
        half8 hv;
        #pragma unroll
        for (int q = 0; q < 2; q++) {
          float4 e4 = ee[i8 * 2 + q], s4 = se[i8 * 2 + q], r4 = re[i8 * 2 + q];
          float4 t4 = te[i8 * 2 + q], c4 = cb[i8 * 2 + q];
          hv[q * 4 + 0] = (_Float16)fmaxf(e4.x + s4.x + tm * t4.x + r4.x + c4.x, 0.f);
          hv[q * 4 + 1] = (_Float16)fmaxf(e4.y + s4.y + tm * t4.y + r4.y + c4.y, 0.f);
          hv[q * 4 + 2] = (_Float16)fmaxf(e4.z + s4.z + tm * t4.z + r4.z + c4.z, 0.f);
          hv[q * 4 + 3] = (_Float16)fmaxf(e4.w + s4.w + tm * t4.w + r4.w + c4.w, 0.f);
        }
        int k0 = seg * 32 + i8 * 8;
        int byte = r * 512 + k0 * 2; byte ^= ((r & 7) << 4);
        *(half8*)(ab + byte) = hv;
      }
    } else {
      int k2b_ = (seg - 4) * 32;
      float at = att_seq[row], hi = hint_seq[row];
      const float4* wa = (const float4*)(W_b1 + k2b_);
      const float4* wh = (const float4*)(W_b1 + 128 + k2b_);
      const float4* bb = (const float4*)(b_b1 + k2b_);
      #pragma unroll
      for (int i8 = 0; i8 < 4; i8++) {
        half8 hv;
        #pragma unroll
        for (int q = 0; q < 2; q++) {
          float4 a4 = wa[i8 * 2 + q], h4 = wh[i8 * 2 + q], b4 = bb[i8 * 2 + q];
          hv[q * 4 + 0] = (_Float16)fmaxf(at * a4.x + hi * h4.x + b4.x, 0.f);
          hv[q * 4 + 1] = (_Float16)fmaxf(at * a4.y + hi * h4.y + b4.y, 0.f);
          hv[q * 4 + 2] = (_Float16)fmaxf(at * a4.z + hi * h4.z + b4.z, 0.f);
          hv[q * 4 + 3] = (_Float16)fmaxf(at * a4.w + hi * h4.w + b4.w, 0.f);
        }
        int k0 = 128 + k2b_ + i8 * 8;
        int byte = r * 512 + k0 * 2; byte ^= ((r & 7) << 4);
        *(half8*)(ab + byte) = hv;
      }
    }
  }
  __syncthreads();

  f32x4 acc[4][2] = {};
  const char* ab = (const char*)Ah;
  #pragma unroll
  for (int kt = 0; kt < 8; kt++) {
    #pragma unroll
    for (int mr = 0; mr < 4; mr++) {
      int byte = (mr * 16 + c) * 512 + kt * 64 + g * 16; byte ^= ((c & 7) << 4);
      half8 a = *(const half8*)(ab + byte);
      acc[mr][0] = __builtin_amdgcn_mfma_f32_16x16x32_f16(a, bfr[0][kt], acc[mr][0], 0, 0, 0);
      acc[mr][1] = __builtin_amdgcn_mfma_f32_16x16x32_f16(a, bfr[1][kt], acc[mr][1], 0, 0, 0);
    }
  }

  bool isL = (w < 4);
  float addc[2], wiv[2];
  #pragma unroll
  for (int ncl = 0; ncl < 2; ncl++) {
    int j = w * 32 + ncl * 16 + c;
    if (isL) { addc[ncl] = c_lg[j]; wiv[ncl] = Wiv[j]; }
    else     { addc[ncl] = c_fg[j - 128]; wiv[ncl] = 0.f; }
  }
  #pragma unroll
  for (int mr = 0; mr < 4; mr++) {
    #pragma unroll
    for (int rr = 0; rr < 4; rr++) {
      int rl = mr * 16 + g * 4 + rr;
      int row = rowbase + rl;
      float iv = ivs[rl];
      #pragma unroll
      for (int ncl = 0; ncl < 2; ncl++) {
        float v = acc[mr][ncl][rr] + addc[ncl] + iv * wiv[ncl];
        PRE[(size_t)row * 256 + w * 32 + ncl * 16 + c] = (f16)v;
      }
    }
  }
}

// ---------------- K4: last-step nb fixup ----------------
__global__ __launch_bounds__(128) void k4_fix(
    const float* att_seq, const float* hint_seq,
    const float* W_b1, const float* b_b1,
    const float* M_lnb, const float* fix_l, f16* PRE) {
  int b = blockIdx.x, j = threadIdx.x;
  int row = b * SS + (SS - 1);
  __shared__ float rb_s[128];
  float v = att_seq[row] * W_b1[j] + hint_seq[row] * W_b1[128 + j] + b_b1[j];
  rb_s[j] = fmaxf(v, 0.f);
  __syncthreads();
  float a = fix_l[j];
  for (int m = 0; m < 128; m++) a += rb_s[m] * M_lnb[m * 128 + j];
  PRE[row * 256 + j] = (f16)((float)PRE[row * 256 + j] - a);
}

// ---------------- K5: MFMA scan, raw barriers + conflict-free subtile LDS ----
// State layout in LDS: [K8 = feature>>3][row ^ (K8&3)][e = feature&7] f16.
// A-frag read (lane c,g, k-step t4): K8 = 4*t4+g, row' = c ^ (K8&3) -> one b128.
#define BAR() asm volatile("s_waitcnt lgkmcnt(0)\n\ts_barrier" ::: "memory")

__global__ __launch_bounds__(512) void k5_scan_mfma(
    const f16* PRE, const f16* Wfrag, f16* h_hist) {
  __shared__ _Float16 AhA[2048], AhB[2048], Alg[2048];
  int tid = threadIdx.x;
  int w = tid >> 6, lane = tid & 63;
  int c = lane & 15, g = lane >> 4;
  int b = blockIdx.x;

  if (tid < 256) ((float4*)AhA)[tid] = make_float4(0.f, 0.f, 0.f, 0.f);

  half8 bL[4], bFH[4], bFL[4];
  const half8* wp = (const half8*)Wfrag;
  #pragma unroll
  for (int t4 = 0; t4 < 4; t4++) {
    bL [t4] = wp[((0 * 8 + w) * 4 + t4) * 64 + lane];
    bFH[t4] = wp[((1 * 8 + w) * 4 + t4) * 64 + lane];
    bFL[t4] = wp[((2 * 8 + w) * 4 + t4) * 64 + lane];
  }

  // static LDS byte offsets
  int rd[4], wr[4];
  #pragma unroll
  for (int t4 = 0; t4 < 4; t4++) {
    int K8 = 4 * t4 + g;
    rd[t4] = K8 * 256 + (c ^ (K8 & 3)) * 16;
  }
  {
    int F = 16 * w + c;
    int K8w = F >> 3, q = K8w & 3;
    #pragma unroll
    for (int r = 0; r < 4; r++)
      wr[r] = K8w * 256 + ((4 * g + r) ^ q) * 16 + (F & 7) * 2;
  }

  int col = 16 * w + c;
  const f16* plp[4]; const f16* pfp[4]; f16* hhp[4];
  #pragma unroll
  for (int r = 0; r < 4; r++) {
    int br = b * 16 + g * 4 + r;
    plp[r] = PRE + (size_t)br * SS * 256 + col;
    pfp[r] = plp[r] + 128;
    hhp[r] = h_hist + (size_t)br * SS * 128 + col;
  }
  float hstate[4] = {0.f, 0.f, 0.f, 0.f};
  float preL[4], preF[4];
  f16 nb0L[4], nb0F[4], nb1L[4], nb1F[4];
  #pragma unroll
  for (int r = 0; r < 4; r++) { preL[r] = (float)plp[r][0]; preF[r] = (float)pfp[r][0]; }
  #pragma unroll
  for (int r = 0; r < 4; r++) { nb1L[r] = plp[r][256]; nb1F[r] = pfp[r][256]; }  // t=1
  __syncthreads();

  const f32x4 Z4 = {0.f, 0.f, 0.f, 0.f};

#define STEP(SRC, DST, TT, NIL, NIF, NCL, NCF)                                   \
  {                                                                              \
    int tn = (TT) + 2; if (tn > 511) tn = 511;                                   \
    _Pragma("unroll")                                                            \
    for (int r = 0; r < 4; r++) {                                                \
      NIL[r] = plp[r][(size_t)tn * 256];                                         \
      NIF[r] = pfp[r][(size_t)tn * 256];                                         \
    }                                                                            \
    half8 ha[4];                                                                 \
    _Pragma("unroll")                                                            \
    for (int t4 = 0; t4 < 4; t4++)                                               \
      ha[t4] = *(const half8*)((const char*)(SRC) + rd[t4]);                     \
    f32x4 aLa = Z4, aLb = Z4, aHa = Z4, aHb = Z4;                                \
    aLa = __builtin_amdgcn_mfma_f32_16x16x32_f16(ha[0], bL[0],  aLa, 0, 0, 0);   \
    aHa = __builtin_amdgcn_mfma_f32_16x16x32_f16(ha[0], bFH[0], aHa, 0, 0, 0);   \
    aLb = __builtin_amdgcn_mfma_f32_16x16x32_f16(ha[2], bL[2],  aLb, 0, 0, 0);   \
    aHb = __builtin_amdgcn_mfma_f32_16x16x32_f16(ha[2], bFH[2], aHb, 0, 0, 0);   \
    aLa = __builtin_amdgcn_mfma_f32_16x16x32_f16(ha[1], bL[1],  aLa, 0, 0, 0);   \
    aHa = __builtin_amdgcn_mfma_f32_16x16x32_f16(ha[1], bFH[1], aHa, 0, 0, 0);   \
    aLb = __builtin_amdgcn_mfma_f32_16x16x32_f16(ha[3], bL[3],  aLb, 0, 0, 0);   \
    aHb = __builtin_amdgcn_mfma_f32_16x16x32_f16(ha[3], bFH[3], aHb, 0, 0, 0);   \
    float lgf[4];                                                                \
    _Pragma("unroll")                                                            \
    for (int r = 0; r < 4; r++) {                                                \
      lgf[r] = sigm(aLa[r] + aLb[r] + preL[r]);                                  \
      *(_Float16*)((char*)Alg + wr[r]) = (_Float16)lgf[r];                       \
    }                                                                            \
    BAR();                                                                       \
    half8 la[4];                                                                 \
    _Pragma("unroll")                                                            \
    for (int t4 = 0; t4 < 4; t4++)                                               \
      la[t4] = *(const half8*)((const char*)Alg + rd[t4]);                       \
    f32x4 aFa = Z4, aFb = Z4;                                                    \
    aFa = __builtin_amdgcn_mfma_f32_16x16x32_f16(la[0], bFL[0], aFa, 0, 0, 0);   \
    aFb = __builtin_amdgcn_mfma_f32_16x16x32_f16(la[2], bFL[2], aFb, 0, 0, 0);   \
    aFa = __builtin_amdgcn_mfma_f32_16x16x32_f16(la[1], bFL[1], aFa, 0, 0, 0);   \
    aFb = __builtin_amdgcn_mfma_f32_16x16x32_f16(la[3], bFL[3], aFb, 0, 0, 0);   \
    _Pragma("unroll")                                                            \
    for (int r = 0; r < 4; r++) {                                                \
      float fg = sigm(aHa[r] + aHb[r] + aFa[r] + aFb[r] + preF[r]);              \
      float hn = lgf[r] + fg * hstate[r];                                        \
      hstate[r] = hn;                                                            \
      _Float16 hv = (_Float16)hn;                                                \
      *(_Float16*)((char*)(DST) + wr[r]) = hv;                                   \
      hhp[r][(size_t)(TT) * 128] = hv;                                           \
      preL[r] = (float)NCL[r]; preF[r] = (float)NCF[r];                          \
    }                                                                            \
    BAR();                                                                       \
  }

  for (int it = 0; it < 256; it++) {
    int t0 = it * 2;
    STEP(AhA, AhB, t0,     nb0L, nb0F, nb1L, nb1F);
    STEP(AhB, AhA, t0 + 1, nb1L, nb1F, nb0L, nb0F);
  }
#undef STEP
}

// ---------------- K6: prediction dot-products ----------------
__global__ __launch_bounds__(256) void k6_pred(
    const f16* h_hist, const int* ex_seq, const float* pe,
    const float* W_pred, const float* b_pred, float* out) {
  int tid = threadIdx.x;
  int w = tid >> 6, l = tid & 63, g = l >> 4, li = l & 15;
  int row = blockIdx.x * 16 + w * 4 + g;
  half8 h8 = *(const half8*)(h_hist + (size_t)row * 128 + li * 8);
  const float4* wp = (const float4*)(W_pred + li * 8);
  float4 w0 = wp[0], w1 = wp[1];
  float s = (float)h8[0] * w0.x + (float)h8[1] * w0.y + (float)h8[2] * w0.z + (float)h8[3] * w0.w
          + (float)h8[4] * w1.x + (float)h8[5] * w1.y + (float)h8[6] * w1.z + (float)h8[7] * w1.w;
  #pragma unroll
  for (int m = 1; m < 16; m <<= 1) s += __shfl_xor(s, m);
  if (li == 0) out[row] = sigm(s + pe[ex_seq[row]] + b_pred[0]);
}

extern "C" void kernel_launch(void* const* d_in, const int* in_sizes, int n_in,
                              void* d_out, int out_size, void* d_ws, size_t ws_size,
                              hipStream_t stream) {
  const int*   ex_seq   = (const int*)d_in[0];
  const int*   sk_seq   = (const int*)d_in[1];
  const int*   re_seq   = (const int*)d_in[2];
  const float* time_seq = (const float*)d_in[3];
  const float* interval_seq = (const float*)d_in[4];
  const float* att_seq  = (const float*)d_in[5];
  const float* hint_seq = (const float*)d_in[6];
  // d_in[7] q_matrix: unused
  const float* ex_emb   = (const float*)d_in[8];
  const float* sk_emb   = (const float*)d_in[9];
  const float* re_emb   = (const float*)d_in[10];
  const float* W_time   = (const float*)d_in[11];
  const float* b_time   = (const float*)d_in[12];
  const float* W_int    = (const float*)d_in[13];
  const float* b_int    = (const float*)d_in[14];
  const float* W_b1     = (const float*)d_in[15];
  const float* b_b1     = (const float*)d_in[16];
  const float* W_b2     = (const float*)d_in[17];
  const float* b_b2     = (const float*)d_in[18];
  const float* W_learn  = (const float*)d_in[19];
  const float* b_learn  = (const float*)d_in[20];
  const float* W_forget = (const float*)d_in[21];
  const float* b_forget = (const float*)d_in[22];
  const float* W_pred   = (const float*)d_in[23];
  const float* b_pred   = (const float*)d_in[24];

  char* ws = (char*)d_ws;
  float* Ee    = (float*)(ws);              // 10,240,000
  float* Se    = (float*)(ws + 10240000);
  float* Re    = (float*)(ws + 10496000);
  float* Te    = (float*)(ws + 10497024);
  float* cbias = (float*)(ws + 10497536);
  float* c_lg  = (float*)(ws + 10498048);
  float* c_fg  = (float*)(ws + 10498560);
  float* fix_l = (float*)(ws + 10499072);
  float* Wcat  = (float*)(ws + 10499584);   // 262,144
  float* M_lnb = (float*)(ws + 10761728);   // 65,536
  f16*   PRE   = (f16*)  (ws + 10827264);   // 67,108,864
  f16*   h_hist= (f16*)  (ws + 77936128);   // 33,554,432
  f16*   Wfrag = (f16*)  (ws + 111490560);  // 98,304  -> total 111,588,864
  // aliased scratch:
  f16*   Bfrag = (f16*)  (ws + 77936128);   // aliases h_hist head (dead until k5)
  float* pe    = (float*)(ws + 10499584);   // aliases Wcat (dead after k2b)

  k0_folds<<<dim3(888), dim3(128), 0, stream>>>(
      sk_emb, re_emb, W_time, b_time, W_int, b_int, W_b2, b_b2,
      W_learn, b_learn, W_forget, b_forget,
      Se, Re, Te, cbias, c_lg, c_fg, fix_l, Wcat, M_lnb);
  k1_Ee<<<dim3(2500), dim3(256), 0, stream>>>(ex_emb, W_int, Ee);
  k2_wprep<<<dim3(96), dim3(64), 0, stream>>>(W_learn, W_forget, Wfrag);
  k2b_bprep<<<dim3(128), dim3(64), 0, stream>>>(Wcat, Bfrag);
  k1b_pe<<<dim3(1250), dim3(256), 0, stream>>>(ex_emb, W_pred, pe);
  k3_gemm_mfma<<<dim3(2048), dim3(512), 0, stream>>>(
      ex_seq, sk_seq, re_seq, time_seq, interval_seq, att_seq, hint_seq,
      W_b1, b_b1, W_learn + 256 * 128, Ee, Se, Re, Te, cbias, c_lg, c_fg, Bfrag, PRE);
  k4_fix<<<dim3(256), dim3(128), 0, stream>>>(
      att_seq, hint_seq, W_b1, b_b1, M_lnb, fix_l, PRE);
  k5_scan_mfma<<<dim3(16), dim3(512), 0, stream>>>(PRE, Wfrag, h_hist);
  k6_pred<<<dim3(8192), dim3(256), 0, stream>>>(
      h_hist, ex_seq, pe, W_pred, b_pred, (float*)d_out);
}